// Round 3
// baseline (212.126 us; speedup 1.0000x reference)
//
#include <hip/hip_runtime.h>

// ElasticEmbedding: out[t,:] = residual_embedding[remap[x[t]]] if x[t] is a
// residual id else pretrained_embedding[x[t]].  D = 128 floats (= 32 x 16B).
// remap table (V ints) built in d_ws.  Gather: 32 lanes/token, 16B/lane,
// 4 tokens per group for 4x memory-level parallelism, nontemporal stores so
// the streaming 134 MB output doesn't evict the 61 MB tables from L2/L3.

#define BLOCK 256
#define UNROLL 4

typedef __attribute__((ext_vector_type(4))) float f4;  // native vec: ok for
                                                       // __builtin_nontemporal_store

__global__ void fill_remap_kernel(int* __restrict__ remap, int V) {
    int i = blockIdx.x * blockDim.x + threadIdx.x;
    if (i < V) remap[i] = -1;
}

__global__ void scatter_remap_kernel(int* __restrict__ remap,
                                     const int* __restrict__ ridx, int R) {
    int i = blockIdx.x * blockDim.x + threadIdx.x;
    if (i < R) remap[ridx[i]] = i;
}

__global__ __launch_bounds__(BLOCK) void gather_kernel(
        const int* __restrict__ x,
        const int* __restrict__ remap,
        const f4* __restrict__ pre,   // [V, 32] 16B chunks
        const f4* __restrict__ res,   // [R, 32]
        f4* __restrict__ out,         // [n_tokens, 32]
        int n_tokens, int n_groups) {
    int g    = (blockIdx.x * BLOCK + threadIdx.x) >> 5;   // 32-lane group id
    int lane = threadIdx.x & 31;

    int tok[UNROLL];
    const f4* src[UNROLL];
    bool ok[UNROLL];

    // Issue all id -> remap -> row-pointer chains first (4 independent
    // dependency chains in flight per thread).
    #pragma unroll
    for (int k = 0; k < UNROLL; ++k) {
        tok[k] = g + k * n_groups;
        ok[k]  = tok[k] < n_tokens;
        if (ok[k]) {
            int t = x[tok[k]];        // broadcast across the 32-lane group
            int r = remap[t];         // broadcast
            src[k] = (r >= 0) ? res + (size_t)r * 32
                              : pre + (size_t)t * 32;
        }
    }

    f4 val[UNROLL];
    #pragma unroll
    for (int k = 0; k < UNROLL; ++k)
        if (ok[k]) val[k] = src[k][lane];          // 4 outstanding 16B loads

    #pragma unroll
    for (int k = 0; k < UNROLL; ++k)
        if (ok[k])
            __builtin_nontemporal_store(val[k],
                &out[(size_t)tok[k] * 32 + lane]); // coalesced 1KB/wave/slot
}

extern "C" void kernel_launch(void* const* d_in, const int* in_sizes, int n_in,
                              void* d_out, int out_size, void* d_ws, size_t ws_size,
                              hipStream_t stream) {
    const int* x    = (const int*)d_in[0];     // [B*S] token ids
    const int* ridx = (const int*)d_in[1];     // [R] sorted residual ids
    const f4*  pre  = (const f4*)d_in[2];      // [V, D/4]
    const f4*  res  = (const f4*)d_in[3];      // [R, D/4]
    f4*        out  = (f4*)d_out;

    const int n_tokens = in_sizes[0];
    const int R        = in_sizes[1];
    const int D        = in_sizes[3] / R;      // 128
    const int V        = in_sizes[2] / D;      // 100000
    (void)ws_size;

    int* remap = (int*)d_ws;                   // V ints = 400 KB scratch

    fill_remap_kernel<<<(V + 255) / 256, 256, 0, stream>>>(remap, V);
    scatter_remap_kernel<<<(R + 255) / 256, 256, 0, stream>>>(remap, ridx, R);

    int n_groups = (n_tokens + UNROLL - 1) / UNROLL;          // tokens / 4
    int threads  = n_groups * 32;
    int blocks   = (threads + BLOCK - 1) / BLOCK;
    gather_kernel<<<blocks, BLOCK, 0, stream>>>(x, remap, pre, res, out,
                                                n_tokens, n_groups);
}